// Round 7
// baseline (441.656 us; speedup 1.0000x reference)
//
#include <hip/hip_runtime.h>
#include <hip/hip_bf16.h>
#include <math.h>

// ---------------------------------------------------------------------------
// Round 7 = round-5 design with two bugs fixed:
//  BUG1 (absmax 8.45): prep cast section had thresholds /8 with only 96 blocks
//        -> only 1/8 of weights cast, rest stayed 0xAA poison. Restored to 768
//        cast blocks (prep grid 1537).
//  BUG2 (latent race): fused BN-finalize lacked __syncthreads() between sums
//        atomics and the cnt atomic -> last block could read incomplete sums.
//        Fixed: atomics -> __threadfence -> __syncthreads -> cnt.
// Design (unmeasured until now):
//  - Frag-linear Q/K/V layouts: every attn operand load = contiguous 1KB b128.
//  - BN folding: K raw (folds into Q~), V raw (BN commutes to epilogue).
//  - qkv/merge/fc1 GEMM outputs bf16; fc2 fp32.
//  - bn_finalize fused into GEMM last-block epilogue (atomic counter).
// MFMA 16x16x32_bf16: A/B row = lane&15, k=(lane>>4)*8+j;
// C/D col=lane&15, row=(lane>>4)*4+reg (m89).
// ---------------------------------------------------------------------------

#define NPIX 1024
typedef __attribute__((ext_vector_type(8))) short short8;
typedef __attribute__((ext_vector_type(4))) float f32x4;
typedef unsigned long long ull;

__device__ __forceinline__ float gelu_exact(float v) {
    return 0.5f * v * (1.0f + erff(v * 0.70710678118654752f));
}
__device__ __forceinline__ short f2bf(float f) {   // RNE float->bf16
    unsigned u = __float_as_uint(f);
    unsigned r = (u + 0x7fffu + ((u >> 16) & 1u)) >> 16;
    return (short)r;
}
__device__ __forceinline__ float bf2f(short s) {
    return __uint_as_float(((unsigned)(unsigned short)s) << 16);
}
__device__ __forceinline__ ull pack4bf(float a, float b, float c, float d) {
    return  (ull)(unsigned short)f2bf(a)
         | ((ull)(unsigned short)f2bf(b) << 16)
         | ((ull)(unsigned short)f2bf(c) << 32)
         | ((ull)(unsigned short)f2bf(d) << 48);
}

// ---------------------------------------------------------------------------
// prep: bid 0..767 x-transpose; 768..1535 weight casts (196608 float8 units);
//       1536 zero sums/cnt.
// ---------------------------------------------------------------------------
__global__ __launch_bounds__(256) void prep_kernel(
    const float* __restrict__ x,
    const float* __restrict__ s0, const float* __restrict__ s1,
    const float* __restrict__ s2, const float* __restrict__ s3,
    short* __restrict__ d0, short* __restrict__ d1,
    short* __restrict__ d2, short* __restrict__ d3,
    short* __restrict__ x_bf, float* __restrict__ x_tf,
    float* __restrict__ sums, int* __restrict__ cnt)
{
    const int bid = blockIdx.x, tid = threadIdx.x;
    if (bid < 768) {
        __shared__ float ls[64][65];
        const int n0 = (bid & 15) * 64;
        const int cy = (bid >> 4) % 6, b = (bid >> 4) / 6;
        const int c0 = cy * 64;
        const int rl = tid >> 6, ll = tid & 63;
        #pragma unroll
        for (int it = 0; it < 16; ++it) {
            int c = rl + it * 4;
            ls[c][ll] = x[((size_t)b * 384 + c0 + c) * NPIX + n0 + ll];
        }
        __syncthreads();
        #pragma unroll
        for (int it = 0; it < 16; ++it) {
            int n = rl + it * 4;
            float v = ls[ll][n];
            size_t row = (size_t)b * NPIX + n0 + n;
            x_tf[row * 384 + c0 + ll] = v;
            x_bf[row * 384 + c0 + ll] = f2bf(v);
        }
    } else if (bid < 1536) {
        int t = (bid - 768) * 256 + tid;          // 0..196607 float8 units
        const float* s; short* d; int off;
        if (t < 73728)       { s = s0; d = d0; off = t; }
        else if (t < 122880) { s = s1; d = d1; off = t - 73728; }
        else if (t < 159744) { s = s2; d = d2; off = t - 122880; }
        else                 { s = s3; d = d3; off = t - 159744; }
        float4 a = *(const float4*)&s[(size_t)off * 8];
        float4 b = *(const float4*)&s[(size_t)off * 8 + 4];
        *(ull*)&d[(size_t)off * 8]     = pack4bf(a.x, a.y, a.z, a.w);
        *(ull*)&d[(size_t)off * 8 + 4] = pack4bf(b.x, b.y, b.z, b.w);
    } else {
        for (int i = tid; i < 6144; i += 256) sums[i] = 0.f;
        if (tid < 4) cnt[tid] = 0;
    }
}

// ---------------------------------------------------------------------------
// GEMM bf16 MFMA: D[row][o] = sum_k A[row][k]*Wt[o][k]. 128x128, BK=64,
// 4 waves, fused BN-stat atomics + last-block BN finalize into st.
// ---------------------------------------------------------------------------
template<typename OT>
__global__ __launch_bounds__(256) void gemm_bf16(
    const short* __restrict__ A, const short* __restrict__ Wt,
    OT* __restrict__ D, float* __restrict__ sums,
    const float* __restrict__ gamma, const float* __restrict__ beta,
    float* __restrict__ st, int* __restrict__ cnt,
    int O, int K, int nblk)
{
    __shared__ short a_s[128 * 72];
    __shared__ short w_s[128 * 72];
    const int tid = threadIdx.x;
    const int wave = tid >> 6, lane = tid & 63;
    const int l16 = lane & 15, lhi = lane >> 4;
    const int m0 = blockIdx.x * 128, o0 = blockIdx.y * 128;
    const int wm = (wave & 1) * 64, wo = (wave >> 1) * 64;

    f32x4 acc[4][4];
    #pragma unroll
    for (int i = 0; i < 4; ++i)
        #pragma unroll
        for (int j = 0; j < 4; ++j) acc[i][j] = (f32x4){0.f, 0.f, 0.f, 0.f};

    for (int k0 = 0; k0 < K; k0 += 64) {
        #pragma unroll
        for (int it = 0; it < 4; ++it) {
            int idx = tid + it * 256;
            int r = idx >> 3, ch = idx & 7;
            *(float4*)&a_s[r * 72 + ch * 8] =
                *(const float4*)&A[(size_t)(m0 + r) * K + k0 + ch * 8];
            *(float4*)&w_s[r * 72 + ch * 8] =
                *(const float4*)&Wt[(size_t)(o0 + r) * K + k0 + ch * 8];
        }
        __syncthreads();
        #pragma unroll
        for (int kb = 0; kb < 2; ++kb) {
            short8 af[4], wf[4];
            #pragma unroll
            for (int i = 0; i < 4; ++i)
                af[i] = *(const short8*)&a_s[(wm + i * 16 + l16) * 72 + kb * 32 + lhi * 8];
            #pragma unroll
            for (int j = 0; j < 4; ++j)
                wf[j] = *(const short8*)&w_s[(wo + j * 16 + l16) * 72 + kb * 32 + lhi * 8];
            #pragma unroll
            for (int i = 0; i < 4; ++i)
                #pragma unroll
                for (int j = 0; j < 4; ++j)
                    acc[i][j] = __builtin_amdgcn_mfma_f32_16x16x32_bf16(af[i], wf[j], acc[i][j], 0, 0, 0);
        }
        __syncthreads();
    }

    #pragma unroll
    for (int i = 0; i < 4; ++i) {
        #pragma unroll
        for (int r = 0; r < 4; ++r) {
            size_t row = (size_t)(m0 + wm + i * 16 + lhi * 4 + r);
            #pragma unroll
            for (int j = 0; j < 4; ++j) {
                if constexpr (sizeof(OT) == 2)
                    D[row * O + o0 + wo + j * 16 + l16] = f2bf(acc[i][j][r]);
                else
                    D[row * O + o0 + wo + j * 16 + l16] = acc[i][j][r];
            }
        }
    }
    #pragma unroll
    for (int j = 0; j < 4; ++j) {
        float s1 = 0.f, s2 = 0.f;
        #pragma unroll
        for (int i = 0; i < 4; ++i)
            #pragma unroll
            for (int r = 0; r < 4; ++r) { float v = acc[i][j][r]; s1 += v; s2 += v * v; }
        s1 += __shfl_xor(s1, 16); s1 += __shfl_xor(s1, 32);
        s2 += __shfl_xor(s2, 16); s2 += __shfl_xor(s2, 32);
        if (lhi == 0) {
            int col = o0 + wo + j * 16 + l16;
            atomicAdd(&sums[col * 2], s1);
            atomicAdd(&sums[col * 2 + 1], s2);
        }
    }
    // BUG2 fix: every thread fences its own atomics, then block-barrier,
    // THEN one thread bumps the completion counter.
    __threadfence();
    __syncthreads();
    __shared__ int lastf;
    if (tid == 0) lastf = (atomicAdd(cnt, 1) == nblk - 1) ? 1 : 0;
    __syncthreads();
    if (lastf) {
        __threadfence();
        for (int ch = tid; ch < O; ch += 256) {
            float s  = atomicAdd(&sums[ch * 2], 0.0f);      // coherent reads
            float ss = atomicAdd(&sums[ch * 2 + 1], 0.0f);
            float mean = s * (1.0f / 8192.0f);
            float var  = ss * (1.0f / 8192.0f) - mean * mean;
            float sc = gamma[ch] * rsqrtf(var + 1e-5f);
            st[ch * 2] = sc;
            st[ch * 2 + 1] = beta[ch] - mean * sc;
        }
    }
}

// ---------------------------------------------------------------------------
// repack: qkv bf16 [row][1536] -> frag-linear q~/k/v.
//  q_lin[bh][qt32][fq2][lane64][8]  q~ = (scq*qr+shq)*sck*invsq*log2e
//  k_lin[bh][mt16][fm4][lane64][8]  raw copy
//  v_lin[bh][mt16][kc2][fdv8][lane64][8]  raw transpose
// block = (mt 16, bh 64), 256 threads.
// ---------------------------------------------------------------------------
__global__ __launch_bounds__(256) void repack_qkv(
    const short* __restrict__ qkvbf, const float* __restrict__ st,
    short* __restrict__ qlin, short* __restrict__ klin, short* __restrict__ vlin)
{
    __shared__ short ls[64][130];
    const int mt = blockIdx.x, bh = blockIdx.y;
    const int b = bh >> 3, h = bh & 7;
    const int chb = h * 192;
    const int n0 = mt * 64;
    const int t = threadIdx.x;
    const int n = t >> 2, lhi = t & 3, l16 = n & 15;
    const size_t rowb = (size_t)(b * NPIX + n0 + n) * 1536;

    // ---- Q  (fold: q BN, k scale, invsq, log2e)
    {
        const float S = 0.17677669529663687f * 1.4426950408889634f;
        int cq = chb + lhi * 8;
        short8 qr = *(const short8*)&qkvbf[rowb + cq];
        float4 a0 = *(const float4*)&st[cq * 2];
        float4 a1 = *(const float4*)&st[cq * 2 + 4];
        float4 a2 = *(const float4*)&st[cq * 2 + 8];
        float4 a3 = *(const float4*)&st[cq * 2 + 12];
        float4 k0 = *(const float4*)&st[(cq + 32) * 2];
        float4 k1 = *(const float4*)&st[(cq + 32) * 2 + 4];
        float4 k2 = *(const float4*)&st[(cq + 32) * 2 + 8];
        float4 k3 = *(const float4*)&st[(cq + 32) * 2 + 12];
        float q0 = (bf2f(qr[0]) * a0.x + a0.y) * k0.x * S;
        float q1 = (bf2f(qr[1]) * a0.z + a0.w) * k0.z * S;
        float q2 = (bf2f(qr[2]) * a1.x + a1.y) * k1.x * S;
        float q3 = (bf2f(qr[3]) * a1.z + a1.w) * k1.z * S;
        float q4 = (bf2f(qr[4]) * a2.x + a2.y) * k2.x * S;
        float q5 = (bf2f(qr[5]) * a2.z + a2.w) * k2.z * S;
        float q6 = (bf2f(qr[6]) * a3.x + a3.y) * k3.x * S;
        float q7 = (bf2f(qr[7]) * a3.z + a3.w) * k3.z * S;
        int fq = (n >> 4) & 1, qtl = n >> 5;
        size_t qo = (size_t)bh * 32768 +
                    ((((size_t)mt * 2 + qtl) * 2 + fq) * 64 + lhi * 16 + l16) * 8;
        *(ull*)&qlin[qo]     = pack4bf(q0, q1, q2, q3);
        *(ull*)&qlin[qo + 4] = pack4bf(q4, q5, q6, q7);
    }
    // ---- K (raw relayout)
    {
        short8 kr = *(const short8*)&qkvbf[rowb + chb + 32 + lhi * 8];
        int fm = n >> 4;
        size_t ko = (size_t)bh * 32768 +
                    (((size_t)mt * 4 + fm) * 64 + lhi * 16 + l16) * 8;
        *(short8*)&klin[ko] = kr;
    }
    // ---- V stage to LDS [64 n][128 dv]
    #pragma unroll
    for (int i = 0; i < 4; ++i) {
        short8 v8 = *(const short8*)&qkvbf[rowb + chb + 64 + lhi * 32 + i * 8];
        *(short8*)&ls[n][lhi * 32 + i * 8] = v8;
    }
    __syncthreads();
    // ---- V gather: frag-linear write, fully coalesced
    #pragma unroll
    for (int u = 0; u < 4; ++u) {
        int unit = t + u * 256;                 // 0..1023
        int kc = unit >> 9, fdv = (unit >> 6) & 7, lane = unit & 63;
        int lh = lane >> 4, l1 = lane & 15;
        int col = fdv * 16 + l1;
        int rbase = kc * 32 + lh * 8;
        short v8[8];
        #pragma unroll
        for (int e = 0; e < 8; ++e) v8[e] = ls[rbase + e][col];
        size_t vo = (size_t)bh * 131072 +
                    (((size_t)mt * 2 + kc) * 8 + fdv) * 512 + (size_t)lane * 8;
        ull u0 =  (ull)(unsigned short)v8[0] | ((ull)(unsigned short)v8[1] << 16)
               | ((ull)(unsigned short)v8[2] << 32) | ((ull)(unsigned short)v8[3] << 48);
        ull u1 =  (ull)(unsigned short)v8[4] | ((ull)(unsigned short)v8[5] << 16)
               | ((ull)(unsigned short)v8[6] << 32) | ((ull)(unsigned short)v8[7] << 48);
        *(ull*)&vlin[vo]     = u0;
        *(ull*)&vlin[vo + 4] = u1;
    }
}

// ---------------------------------------------------------------------------
// Flash attention, swapped-QK^T, frag-linear operands (all loads contiguous
// 1KB b128). 1 wave/block, 2048 blocks XCD-swizzled. V BN applied in epilogue.
// ---------------------------------------------------------------------------
#define ATTN_TILE(TT, KCUR, KNEXT)                                            \
{                                                                             \
    const int tt_ = (TT);                                                     \
    f32x4 s0_[4], s1_[4];                                                     \
    _Pragma("unroll")                                                         \
    for (int fm = 0; fm < 4; ++fm) {                                          \
        s0_[fm] = (f32x4){0.f, 0.f, 0.f, 0.f};                                \
        s1_[fm] = (f32x4){0.f, 0.f, 0.f, 0.f};                                \
    }                                                                         \
    _Pragma("unroll")                                                         \
    for (int fm = 0; fm < 4; ++fm) {                                          \
        s0_[fm] = __builtin_amdgcn_mfma_f32_16x16x32_bf16(KCUR[fm], qf0, s0_[fm], 0, 0, 0); \
        s1_[fm] = __builtin_amdgcn_mfma_f32_16x16x32_bf16(KCUR[fm], qf1, s1_[fm], 0, 0, 0); \
    }                                                                         \
    short8 vf_[16];                                                           \
    _Pragma("unroll")                                                         \
    for (int kc = 0; kc < 2; ++kc)                                            \
        _Pragma("unroll")                                                     \
        for (int fdv = 0; fdv < 8; ++fdv)                                     \
            vf_[kc * 8 + fdv] = *(const short8*)&vb[((((size_t)tt_ * 2 + kc) * 8 + fdv) * 64 + lane) * 8]; \
    {                                                                         \
        int tn_ = (tt_ + 1) & 15;                                             \
        _Pragma("unroll")                                                     \
        for (int fm = 0; fm < 4; ++fm)                                        \
            KNEXT[fm] = *(const short8*)&kb[((((size_t)tn_ * 4 + fm) * 64) + lane) * 8]; \
    }                                                                         \
    float mx0 = fmaxf(fmaxf(s0_[0][0], s0_[0][1]), fmaxf(s0_[0][2], s0_[0][3])); \
    float mx1 = fmaxf(fmaxf(s1_[0][0], s1_[0][1]), fmaxf(s1_[0][2], s1_[0][3])); \
    _Pragma("unroll")                                                         \
    for (int fm = 1; fm < 4; ++fm) {                                          \
        mx0 = fmaxf(mx0, fmaxf(fmaxf(s0_[fm][0], s0_[fm][1]), fmaxf(s0_[fm][2], s0_[fm][3]))); \
        mx1 = fmaxf(mx1, fmaxf(fmaxf(s1_[fm][0], s1_[fm][1]), fmaxf(s1_[fm][2], s1_[fm][3]))); \
    }                                                                         \
    mx0 = fmaxf(mx0, __shfl_xor(mx0, 16)); mx0 = fmaxf(mx0, __shfl_xor(mx0, 32)); \
    mx1 = fmaxf(mx1, __shfl_xor(mx1, 16)); mx1 = fmaxf(mx1, __shfl_xor(mx1, 32)); \
    bool need_ = (mx0 > m_run0 + 11.0f) || (mx1 > m_run1 + 11.0f);            \
    if (__any(need_)) {                                                       \
        float mn0 = fmaxf(m_run0, mx0), f0 = exp2f(m_run0 - mn0);             \
        float mn1 = fmaxf(m_run1, mx1), f1 = exp2f(m_run1 - mn1);             \
        m_run0 = mn0; m_run1 = mn1; l_run0 *= f0; l_run1 *= f1;               \
        _Pragma("unroll")                                                     \
        for (int rr = 0; rr < 4; ++rr) {                                      \
            float fb0 = __shfl(f0, lhi * 4 + rr);                             \
            float fb1 = __shfl(f1, lhi * 4 + rr);                             \
            _Pragma("unroll")                                                 \
            for (int fdv = 0; fdv < 8; ++fdv) {                               \
                acc[0][fdv][rr] *= fb0;                                       \
                acc[1][fdv][rr] *= fb1;                                       \
            }                                                                 \
        }                                                                     \
    }                                                                         \
    float rs0 = 0.f, rs1 = 0.f;                                               \
    _Pragma("unroll")                                                         \
    for (int fm = 0; fm < 4; ++fm) {                                          \
        float p0 = exp2f(s0_[fm][0] - m_run0), p1 = exp2f(s0_[fm][1] - m_run0); \
        float p2 = exp2f(s0_[fm][2] - m_run0), p3 = exp2f(s0_[fm][3] - m_run0); \
        rs0 += (p0 + p1) + (p2 + p3);                                         \
        *(ull*)&pw[l16 * 72 + fm * 16 + lhi * 4] = pack4bf(p0, p1, p2, p3);   \
        float t0 = exp2f(s1_[fm][0] - m_run1), t1 = exp2f(s1_[fm][1] - m_run1); \
        float t2 = exp2f(s1_[fm][2] - m_run1), t3 = exp2f(s1_[fm][3] - m_run1); \
        rs1 += (t0 + t1) + (t2 + t3);                                         \
        *(ull*)&pw[(16 + l16) * 72 + fm * 16 + lhi * 4] = pack4bf(t0, t1, t2, t3); \
    }                                                                         \
    rs0 += __shfl_xor(rs0, 16); rs0 += __shfl_xor(rs0, 32);                   \
    rs1 += __shfl_xor(rs1, 16); rs1 += __shfl_xor(rs1, 32);                   \
    l_run0 += rs0; l_run1 += rs1;                                             \
    asm volatile("s_waitcnt lgkmcnt(0)" ::: "memory");                        \
    _Pragma("unroll")                                                         \
    for (int kc = 0; kc < 2; ++kc) {                                          \
        short8 pf0 = *(const short8*)&pw[l16 * 72 + kc * 32 + lhi * 8];       \
        short8 pf1 = *(const short8*)&pw[(16 + l16) * 72 + kc * 32 + lhi * 8]; \
        _Pragma("unroll")                                                     \
        for (int fdv = 0; fdv < 8; ++fdv) {                                   \
            acc[0][fdv] = __builtin_amdgcn_mfma_f32_16x16x32_bf16(pf0, vf_[kc * 8 + fdv], acc[0][fdv], 0, 0, 0); \
            acc[1][fdv] = __builtin_amdgcn_mfma_f32_16x16x32_bf16(pf1, vf_[kc * 8 + fdv], acc[1][fdv], 0, 0, 0); \
        }                                                                     \
    }                                                                         \
}

__global__ __launch_bounds__(64) void attn_kernel(
    const short* __restrict__ qlin, const short* __restrict__ klin,
    const short* __restrict__ vlin, const float* __restrict__ st,
    short* __restrict__ outp)
{
    __shared__ short pw[32 * 72];
    const int id0 = blockIdx.x;                       // 2048
    const int swz = (id0 & 7) * 256 + (id0 >> 3);     // XCD-contiguous chunks
    const int qt = swz & 31, bh = swz >> 5;
    const int h = bh & 7, b = bh >> 3;
    const int q0 = qt * 32;
    const int lane = threadIdx.x;
    const int l16 = lane & 15, lhi = lane >> 4;

    const short* qb = qlin + (size_t)bh * 32768;
    const short* kb = klin + (size_t)bh * 32768;
    const short* vb = vlin + (size_t)bh * 131072;

    short8 qf0 = *(const short8*)&qb[(((size_t)qt * 2 + 0) * 64 + lane) * 8];
    short8 qf1 = *(const short8*)&qb[(((size_t)qt * 2 + 1) * 64 + lane) * 8];

    f32x4 acc[2][8];
    #pragma unroll
    for (int i = 0; i < 2; ++i)
        #pragma unroll
        for (int j = 0; j < 8; ++j) acc[i][j] = (f32x4){0.f, 0.f, 0.f, 0.f};
    float m_run0 = -1e30f, m_run1 = -1e30f, l_run0 = 0.f, l_run1 = 0.f;

    short8 kfA[4], kfB[4];
    #pragma unroll
    for (int fm = 0; fm < 4; ++fm)
        kfA[fm] = *(const short8*)&kb[((size_t)fm * 64 + lane) * 8];

    for (int mt = 0; mt < 16; mt += 2) {
        ATTN_TILE(mt,     kfA, kfB)
        ATTN_TILE(mt + 1, kfB, kfA)
    }

    // epilogue: V BN (commuted), normalize, gelu, store
    float scv[8], shv[8];
    #pragma unroll
    for (int fdv = 0; fdv < 8; ++fdv) {
        int cv = h * 192 + 64 + fdv * 16 + l16;
        scv[fdv] = st[cv * 2]; shv[fdv] = st[cv * 2 + 1];
    }
    #pragma unroll
    for (int rr = 0; rr < 4; ++rr) {
        float inv0 = 1.0f / __shfl(l_run0, lhi * 4 + rr);
        float inv1 = 1.0f / __shfl(l_run1, lhi * 4 + rr);
        size_t row0 = (size_t)b * NPIX + q0 + lhi * 4 + rr;
        #pragma unroll
        for (int fdv = 0; fdv < 8; ++fdv) {
            float o0 = acc[0][fdv][rr] * inv0 * scv[fdv] + shv[fdv];
            float o1 = acc[1][fdv][rr] * inv1 * scv[fdv] + shv[fdv];
            outp[row0 * 1024 + h * 128 + fdv * 16 + l16] = f2bf(gelu_exact(o0));
            outp[(row0 + 16) * 1024 + h * 128 + fdv * 16 + l16] = f2bf(gelu_exact(o1));
        }
    }
}

// ---------------------------------------------------------------------------
// x2 = x_tf + bn(merge_bf); writes fp32 + bf16. 8 ch/thread.
// ---------------------------------------------------------------------------
__global__ __launch_bounds__(256) void x2_kernel(
    const short* __restrict__ raw, const float* __restrict__ st,
    const float* __restrict__ xtf, float* __restrict__ x2f, short* __restrict__ x2bf)
{
    int t = blockIdx.x * 256 + threadIdx.x;     // ROWS*48
    int row = t / 48, c = (t % 48) * 8;
    size_t idx = (size_t)row * 384 + c;
    short8 v8 = *(const short8*)&raw[idx];
    float o[8];
    #pragma unroll
    for (int j = 0; j < 8; ++j) {
        float sc = st[(c + j) * 2], sh = st[(c + j) * 2 + 1];
        o[j] = xtf[idx + j] + bf2f(v8[j]) * sc + sh;
    }
    *(float4*)&x2f[idx]     = make_float4(o[0], o[1], o[2], o[3]);
    *(float4*)&x2f[idx + 4] = make_float4(o[4], o[5], o[6], o[7]);
    *(ull*)&x2bf[idx]     = pack4bf(o[0], o[1], o[2], o[3]);
    *(ull*)&x2bf[idx + 4] = pack4bf(o[4], o[5], o[6], o[7]);
}

// ---------------------------------------------------------------------------
// h = gelu(bn(fc1_bf)) -> bf16. 8 ch/thread.
// ---------------------------------------------------------------------------
__global__ __launch_bounds__(256) void h_kernel(
    const short* __restrict__ raw, const float* __restrict__ st, short* __restrict__ hbf)
{
    int t = blockIdx.x * 256 + threadIdx.x;     // ROWS*96
    int row = t / 96, c = (t % 96) * 8;
    size_t idx = (size_t)row * 768 + c;
    short8 v8 = *(const short8*)&raw[idx];
    float o[8];
    #pragma unroll
    for (int j = 0; j < 8; ++j) {
        float sc = st[(c + j) * 2], sh = st[(c + j) * 2 + 1];
        o[j] = gelu_exact(bf2f(v8[j]) * sc + sh);
    }
    *(ull*)&hbf[idx]     = pack4bf(o[0], o[1], o[2], o[3]);
    *(ull*)&hbf[idx + 4] = pack4bf(o[4], o[5], o[6], o[7]);
}

// ---------------------------------------------------------------------------
// out[b][c][n] = x2f[row][c] + bn(fc2_raw[row][c])  (transposed store)
// ---------------------------------------------------------------------------
__global__ __launch_bounds__(256) void final_tr(
    const float* __restrict__ raw, const float* __restrict__ st,
    const float* __restrict__ x2f, float* __restrict__ out)
{
    __shared__ float ls[64][65];
    const int b = blockIdx.z, c0 = blockIdx.y * 64, n0 = blockIdx.x * 64;
    const int rl = threadIdx.x >> 6, ll = threadIdx.x & 63;
    const int c = c0 + ll;
    const float sc = st[c * 2], sh = st[c * 2 + 1];
    #pragma unroll
    for (int it = 0; it < 16; ++it) {
        int n = rl + it * 4;
        size_t idx = ((size_t)b * NPIX + n0 + n) * 384 + c;
        ls[n][ll] = x2f[idx] + raw[idx] * sc + sh;
    }
    __syncthreads();
    #pragma unroll
    for (int it = 0; it < 16; ++it) {
        int cr = rl + it * 4;
        out[((size_t)b * 384 + c0 + cr) * NPIX + n0 + ll] = ls[ll][cr];
    }
}

// ---------------------------------------------------------------------------
extern "C" void kernel_launch(void* const* d_in, const int* in_sizes, int n_in,
                              void* d_out, int out_size, void* d_ws, size_t ws_size,
                              hipStream_t stream)
{
    const float* x       = (const float*)d_in[0];
    const float* w_qkv   = (const float*)d_in[1];
    const float* g_qkv   = (const float*)d_in[2];
    const float* b_qkv   = (const float*)d_in[3];
    const float* w_merge = (const float*)d_in[4];
    const float* g_merge = (const float*)d_in[5];
    const float* b_merge = (const float*)d_in[6];
    const float* w_fc1   = (const float*)d_in[7];
    const float* g_fc1   = (const float*)d_in[8];
    const float* b_fc1   = (const float*)d_in[9];
    const float* w_fc2   = (const float*)d_in[10];
    const float* g_fc2   = (const float*)d_in[11];
    const float* b_fc2   = (const float*)d_in[12];
    float* out = (float*)d_out;

    char* ws = (char*)d_ws;
    short* wq_bf   = (short*)(ws + 0);
    short* wm_bf   = (short*)(ws + 1179648);
    short* wf1_bf  = (short*)(ws + 1966080);
    short* wf2_bf  = (short*)(ws + 2555904);
    short* x_bf    = (short*)(ws + 3145728);      // 6,291,456
    float* x_tf    = (float*)(ws + 9437184);      // 12,582,912
    short* qkv_bf  = (short*)(ws + 22020096);     // 25,165,824 (dead after repack)
    short* attn_bf = (short*)(ws + 22020096);     // 16,777,216 (reuse, after repack)
    float* fc2_raw = (float*)(ws + 22020096);     // 12,582,912 (reuse, after merge gemm)
    short* q_lin   = (short*)(ws + 47185920);     // 4,194,304
    short* merge_bf= (short*)(ws + 47185920);     // 6,291,456 (reuse q/k_lin after attn)
    short* k_lin   = (short*)(ws + 51380224);     // 4,194,304
    short* v_lin   = (short*)(ws + 55574528);     // 16,777,216
    float* x2_f    = (float*)(ws + 55574528);     // 12,582,912 (reuse v_lin after attn)
    short* x2_bf   = (short*)(ws + 72351744);     // 6,291,456
    short* fc1_bf  = (short*)(ws + 78643200);     // 12,582,912
    short* h_bf    = (short*)(ws + 91226112);     // 12,582,912
    float* sums    = (float*)(ws + 103809024);    // 24,576
    float* stats   = (float*)(ws + 103833600);    // 24,576
    int*   cnt     = (int*)  (ws + 103858176);    // 16

    float* sums_qkv = sums;
    float* sums_mg  = sums + 1536 * 2;
    float* sums_f1  = sums + (1536 + 384) * 2;
    float* sums_f2  = sums + (1536 + 384 + 768) * 2;
    float* st_qkv = stats;
    float* st_mg  = stats + 1536 * 2;
    float* st_f1  = stats + (1536 + 384) * 2;
    float* st_f2  = stats + (1536 + 384 + 768) * 2;

    prep_kernel<<<1537, 256, 0, stream>>>(x, w_qkv, w_merge, w_fc1, w_fc2,
                                          wq_bf, wm_bf, wf1_bf, wf2_bf,
                                          x_bf, x_tf, sums, cnt);

    gemm_bf16<short><<<dim3(64, 12), 256, 0, stream>>>(
        x_bf, wq_bf, qkv_bf, sums_qkv, g_qkv, b_qkv, st_qkv, cnt + 0, 1536, 384, 768);

    repack_qkv<<<dim3(16, 64), 256, 0, stream>>>(qkv_bf, st_qkv, q_lin, k_lin, v_lin);

    attn_kernel<<<2048, 64, 0, stream>>>(q_lin, k_lin, v_lin, st_qkv, attn_bf);

    gemm_bf16<short><<<dim3(64, 3), 256, 0, stream>>>(
        attn_bf, wm_bf, merge_bf, sums_mg, g_merge, b_merge, st_mg, cnt + 1, 384, 1024, 192);

    x2_kernel<<<1536, 256, 0, stream>>>(merge_bf, st_mg, x_tf, x2_f, x2_bf);

    gemm_bf16<short><<<dim3(64, 6), 256, 0, stream>>>(
        x2_bf, wf1_bf, fc1_bf, sums_f1, g_fc1, b_fc1, st_f1, cnt + 2, 768, 384, 384);

    h_kernel<<<3072, 256, 0, stream>>>(fc1_bf, st_f1, h_bf);

    gemm_bf16<float><<<dim3(64, 3), 256, 0, stream>>>(
        h_bf, wf2_bf, fc2_raw, sums_f2, g_fc2, b_fc2, st_f2, cnt + 3, 384, 768, 192);

    final_tr<<<dim3(16, 6, 8), 256, 0, stream>>>(fc2_raw, st_f2, x2_f, out);
}

// Round 8
// 300.548 us; speedup vs baseline: 1.4695x; 1.4695x over previous
//
#include <hip/hip_runtime.h>
#include <hip/hip_bf16.h>
#include <math.h>

// ---------------------------------------------------------------------------
// Round 8 = round 7 minus the fused BN-finalize (the regression).
//  ROOT CAUSE (r7): per-block __threadfence() in every GEMM = device-scope
//  release on non-coherent per-XCD L2s -> per-block L2 writeback storms.
//  qkv gemm: 125us at MfmaUtil 3% / VALU 4.6% (97% cache-maintenance stall).
//  FIX: separate bn_finalize launches (kernel-boundary coherence is ~free);
//  GEMM keeps only the un-fenced per-column atomics (measured fine r2-r4).
// Kept from r7: frag-linear Q/K/V attn operands, BN folds (K->Q~, V->epilogue),
//  bf16 GEMM outputs, fused prep.
// MFMA 16x16x32_bf16: A/B row = lane&15, k=(lane>>4)*8+j;
// C/D col=lane&15, row=(lane>>4)*4+reg (m89).
// ---------------------------------------------------------------------------

#define NPIX 1024
typedef __attribute__((ext_vector_type(8))) short short8;
typedef __attribute__((ext_vector_type(4))) float f32x4;
typedef unsigned long long ull;

__device__ __forceinline__ float gelu_exact(float v) {
    return 0.5f * v * (1.0f + erff(v * 0.70710678118654752f));
}
__device__ __forceinline__ short f2bf(float f) {   // RNE float->bf16
    unsigned u = __float_as_uint(f);
    unsigned r = (u + 0x7fffu + ((u >> 16) & 1u)) >> 16;
    return (short)r;
}
__device__ __forceinline__ float bf2f(short s) {
    return __uint_as_float(((unsigned)(unsigned short)s) << 16);
}
__device__ __forceinline__ ull pack4bf(float a, float b, float c, float d) {
    return  (ull)(unsigned short)f2bf(a)
         | ((ull)(unsigned short)f2bf(b) << 16)
         | ((ull)(unsigned short)f2bf(c) << 32)
         | ((ull)(unsigned short)f2bf(d) << 48);
}

// ---------------------------------------------------------------------------
// prep: bid 0..767 x-transpose; 768..1535 weight casts (196608 float8 units);
//       1536 zero sums.
// ---------------------------------------------------------------------------
__global__ __launch_bounds__(256) void prep_kernel(
    const float* __restrict__ x,
    const float* __restrict__ s0, const float* __restrict__ s1,
    const float* __restrict__ s2, const float* __restrict__ s3,
    short* __restrict__ d0, short* __restrict__ d1,
    short* __restrict__ d2, short* __restrict__ d3,
    short* __restrict__ x_bf, float* __restrict__ x_tf,
    float* __restrict__ sums)
{
    const int bid = blockIdx.x, tid = threadIdx.x;
    if (bid < 768) {
        __shared__ float ls[64][65];
        const int n0 = (bid & 15) * 64;
        const int cy = (bid >> 4) % 6, b = (bid >> 4) / 6;
        const int c0 = cy * 64;
        const int rl = tid >> 6, ll = tid & 63;
        #pragma unroll
        for (int it = 0; it < 16; ++it) {
            int c = rl + it * 4;
            ls[c][ll] = x[((size_t)b * 384 + c0 + c) * NPIX + n0 + ll];
        }
        __syncthreads();
        #pragma unroll
        for (int it = 0; it < 16; ++it) {
            int n = rl + it * 4;
            float v = ls[ll][n];
            size_t row = (size_t)b * NPIX + n0 + n;
            x_tf[row * 384 + c0 + ll] = v;
            x_bf[row * 384 + c0 + ll] = f2bf(v);
        }
    } else if (bid < 1536) {
        int t = (bid - 768) * 256 + tid;          // 0..196607 float8 units
        const float* s; short* d; int off;
        if (t < 73728)       { s = s0; d = d0; off = t; }
        else if (t < 122880) { s = s1; d = d1; off = t - 73728; }
        else if (t < 159744) { s = s2; d = d2; off = t - 122880; }
        else                 { s = s3; d = d3; off = t - 159744; }
        float4 a = *(const float4*)&s[(size_t)off * 8];
        float4 b = *(const float4*)&s[(size_t)off * 8 + 4];
        *(ull*)&d[(size_t)off * 8]     = pack4bf(a.x, a.y, a.z, a.w);
        *(ull*)&d[(size_t)off * 8 + 4] = pack4bf(b.x, b.y, b.z, b.w);
    } else {
        for (int i = tid; i < 6144; i += 256) sums[i] = 0.f;
    }
}

// ---------------------------------------------------------------------------
// GEMM bf16 MFMA: D[row][o] = sum_k A[row][k]*Wt[o][k]. 128x128, BK=64,
// 4 waves, fused BN-stat atomics (NO fences, NO finalize tail).
// ---------------------------------------------------------------------------
template<typename OT>
__global__ __launch_bounds__(256) void gemm_bf16(
    const short* __restrict__ A, const short* __restrict__ Wt,
    OT* __restrict__ D, float* __restrict__ sums, int O, int K)
{
    __shared__ short a_s[128 * 72];
    __shared__ short w_s[128 * 72];
    const int tid = threadIdx.x;
    const int wave = tid >> 6, lane = tid & 63;
    const int l16 = lane & 15, lhi = lane >> 4;
    const int m0 = blockIdx.x * 128, o0 = blockIdx.y * 128;
    const int wm = (wave & 1) * 64, wo = (wave >> 1) * 64;

    f32x4 acc[4][4];
    #pragma unroll
    for (int i = 0; i < 4; ++i)
        #pragma unroll
        for (int j = 0; j < 4; ++j) acc[i][j] = (f32x4){0.f, 0.f, 0.f, 0.f};

    for (int k0 = 0; k0 < K; k0 += 64) {
        #pragma unroll
        for (int it = 0; it < 4; ++it) {
            int idx = tid + it * 256;
            int r = idx >> 3, ch = idx & 7;
            *(float4*)&a_s[r * 72 + ch * 8] =
                *(const float4*)&A[(size_t)(m0 + r) * K + k0 + ch * 8];
            *(float4*)&w_s[r * 72 + ch * 8] =
                *(const float4*)&Wt[(size_t)(o0 + r) * K + k0 + ch * 8];
        }
        __syncthreads();
        #pragma unroll
        for (int kb = 0; kb < 2; ++kb) {
            short8 af[4], wf[4];
            #pragma unroll
            for (int i = 0; i < 4; ++i)
                af[i] = *(const short8*)&a_s[(wm + i * 16 + l16) * 72 + kb * 32 + lhi * 8];
            #pragma unroll
            for (int j = 0; j < 4; ++j)
                wf[j] = *(const short8*)&w_s[(wo + j * 16 + l16) * 72 + kb * 32 + lhi * 8];
            #pragma unroll
            for (int i = 0; i < 4; ++i)
                #pragma unroll
                for (int j = 0; j < 4; ++j)
                    acc[i][j] = __builtin_amdgcn_mfma_f32_16x16x32_bf16(af[i], wf[j], acc[i][j], 0, 0, 0);
        }
        __syncthreads();
    }

    #pragma unroll
    for (int i = 0; i < 4; ++i) {
        #pragma unroll
        for (int r = 0; r < 4; ++r) {
            size_t row = (size_t)(m0 + wm + i * 16 + lhi * 4 + r);
            #pragma unroll
            for (int j = 0; j < 4; ++j) {
                if constexpr (sizeof(OT) == 2)
                    D[row * O + o0 + wo + j * 16 + l16] = f2bf(acc[i][j][r]);
                else
                    D[row * O + o0 + wo + j * 16 + l16] = acc[i][j][r];
            }
        }
    }
    #pragma unroll
    for (int j = 0; j < 4; ++j) {
        float s1 = 0.f, s2 = 0.f;
        #pragma unroll
        for (int i = 0; i < 4; ++i)
            #pragma unroll
            for (int r = 0; r < 4; ++r) { float v = acc[i][j][r]; s1 += v; s2 += v * v; }
        s1 += __shfl_xor(s1, 16); s1 += __shfl_xor(s1, 32);
        s2 += __shfl_xor(s2, 16); s2 += __shfl_xor(s2, 32);
        if (lhi == 0) {
            int col = o0 + wo + j * 16 + l16;
            atomicAdd(&sums[col * 2], s1);
            atomicAdd(&sums[col * 2 + 1], s2);
        }
    }
}

// ---------------------------------------------------------------------------
__global__ __launch_bounds__(256) void bn_finalize(
    const float* __restrict__ sums, const float* __restrict__ gamma,
    const float* __restrict__ beta, float* __restrict__ st, int O)
{
    int ch = blockIdx.x * 256 + threadIdx.x;
    if (ch >= O) return;
    float s = sums[ch * 2], ss = sums[ch * 2 + 1];
    float mean = s * (1.0f / 8192.0f);
    float var = ss * (1.0f / 8192.0f) - mean * mean;
    float sc = gamma[ch] * rsqrtf(var + 1e-5f);
    st[ch * 2] = sc;
    st[ch * 2 + 1] = beta[ch] - mean * sc;
}

// ---------------------------------------------------------------------------
// repack: qkv bf16 [row][1536] -> frag-linear q~/k/v.
//  q_lin[bh][qt32][fq2][lane64][8]  q~ = (scq*qr+shq)*sck*invsq*log2e
//  k_lin[bh][mt16][fm4][lane64][8]  raw copy
//  v_lin[bh][mt16][kc2][fdv8][lane64][8]  raw transpose
// block = (mt 16, bh 64), 256 threads.
// ---------------------------------------------------------------------------
__global__ __launch_bounds__(256) void repack_qkv(
    const short* __restrict__ qkvbf, const float* __restrict__ st,
    short* __restrict__ qlin, short* __restrict__ klin, short* __restrict__ vlin)
{
    __shared__ short ls[64][130];
    const int mt = blockIdx.x, bh = blockIdx.y;
    const int b = bh >> 3, h = bh & 7;
    const int chb = h * 192;
    const int n0 = mt * 64;
    const int t = threadIdx.x;
    const int n = t >> 2, lhi = t & 3, l16 = n & 15;
    const size_t rowb = (size_t)(b * NPIX + n0 + n) * 1536;

    // ---- Q  (fold: q BN, k scale, invsq, log2e)
    {
        const float S = 0.17677669529663687f * 1.4426950408889634f;
        int cq = chb + lhi * 8;
        short8 qr = *(const short8*)&qkvbf[rowb + cq];
        float4 a0 = *(const float4*)&st[cq * 2];
        float4 a1 = *(const float4*)&st[cq * 2 + 4];
        float4 a2 = *(const float4*)&st[cq * 2 + 8];
        float4 a3 = *(const float4*)&st[cq * 2 + 12];
        float4 k0 = *(const float4*)&st[(cq + 32) * 2];
        float4 k1 = *(const float4*)&st[(cq + 32) * 2 + 4];
        float4 k2 = *(const float4*)&st[(cq + 32) * 2 + 8];
        float4 k3 = *(const float4*)&st[(cq + 32) * 2 + 12];
        float q0 = (bf2f(qr[0]) * a0.x + a0.y) * k0.x * S;
        float q1 = (bf2f(qr[1]) * a0.z + a0.w) * k0.z * S;
        float q2 = (bf2f(qr[2]) * a1.x + a1.y) * k1.x * S;
        float q3 = (bf2f(qr[3]) * a1.z + a1.w) * k1.z * S;
        float q4 = (bf2f(qr[4]) * a2.x + a2.y) * k2.x * S;
        float q5 = (bf2f(qr[5]) * a2.z + a2.w) * k2.z * S;
        float q6 = (bf2f(qr[6]) * a3.x + a3.y) * k3.x * S;
        float q7 = (bf2f(qr[7]) * a3.z + a3.w) * k3.z * S;
        int fq = (n >> 4) & 1, qtl = n >> 5;
        size_t qo = (size_t)bh * 32768 +
                    ((((size_t)mt * 2 + qtl) * 2 + fq) * 64 + lhi * 16 + l16) * 8;
        *(ull*)&qlin[qo]     = pack4bf(q0, q1, q2, q3);
        *(ull*)&qlin[qo + 4] = pack4bf(q4, q5, q6, q7);
    }
    // ---- K (raw relayout)
    {
        short8 kr = *(const short8*)&qkvbf[rowb + chb + 32 + lhi * 8];
        int fm = n >> 4;
        size_t ko = (size_t)bh * 32768 +
                    (((size_t)mt * 4 + fm) * 64 + lhi * 16 + l16) * 8;
        *(short8*)&klin[ko] = kr;
    }
    // ---- V stage to LDS [64 n][128 dv]
    #pragma unroll
    for (int i = 0; i < 4; ++i) {
        short8 v8 = *(const short8*)&qkvbf[rowb + chb + 64 + lhi * 32 + i * 8];
        *(short8*)&ls[n][lhi * 32 + i * 8] = v8;
    }
    __syncthreads();
    // ---- V gather: frag-linear write, fully coalesced
    #pragma unroll
    for (int u = 0; u < 4; ++u) {
        int unit = t + u * 256;                 // 0..1023
        int kc = unit >> 9, fdv = (unit >> 6) & 7, lane = unit & 63;
        int lh = lane >> 4, l1 = lane & 15;
        int col = fdv * 16 + l1;
        int rbase = kc * 32 + lh * 8;
        short v8[8];
        #pragma unroll
        for (int e = 0; e < 8; ++e) v8[e] = ls[rbase + e][col];
        size_t vo = (size_t)bh * 131072 +
                    (((size_t)mt * 2 + kc) * 8 + fdv) * 512 + (size_t)lane * 8;
        ull u0 =  (ull)(unsigned short)v8[0] | ((ull)(unsigned short)v8[1] << 16)
               | ((ull)(unsigned short)v8[2] << 32) | ((ull)(unsigned short)v8[3] << 48);
        ull u1 =  (ull)(unsigned short)v8[4] | ((ull)(unsigned short)v8[5] << 16)
               | ((ull)(unsigned short)v8[6] << 32) | ((ull)(unsigned short)v8[7] << 48);
        *(ull*)&vlin[vo]     = u0;
        *(ull*)&vlin[vo + 4] = u1;
    }
}

// ---------------------------------------------------------------------------
// Flash attention, swapped-QK^T, frag-linear operands (all loads contiguous
// 1KB b128). 1 wave/block, 2048 blocks XCD-swizzled. V BN applied in epilogue.
// ---------------------------------------------------------------------------
#define ATTN_TILE(TT, KCUR, KNEXT)                                            \
{                                                                             \
    const int tt_ = (TT);                                                     \
    f32x4 s0_[4], s1_[4];                                                     \
    _Pragma("unroll")                                                         \
    for (int fm = 0; fm < 4; ++fm) {                                          \
        s0_[fm] = (f32x4){0.f, 0.f, 0.f, 0.f};                                \
        s1_[fm] = (f32x4){0.f, 0.f, 0.f, 0.f};                                \
    }                                                                         \
    _Pragma("unroll")                                                         \
    for (int fm = 0; fm < 4; ++fm) {                                          \
        s0_[fm] = __builtin_amdgcn_mfma_f32_16x16x32_bf16(KCUR[fm], qf0, s0_[fm], 0, 0, 0); \
        s1_[fm] = __builtin_amdgcn_mfma_f32_16x16x32_bf16(KCUR[fm], qf1, s1_[fm], 0, 0, 0); \
    }                                                                         \
    short8 vf_[16];                                                           \
    _Pragma("unroll")                                                         \
    for (int kc = 0; kc < 2; ++kc)                                            \
        _Pragma("unroll")                                                     \
        for (int fdv = 0; fdv < 8; ++fdv)                                     \
            vf_[kc * 8 + fdv] = *(const short8*)&vb[((((size_t)tt_ * 2 + kc) * 8 + fdv) * 64 + lane) * 8]; \
    {                                                                         \
        int tn_ = (tt_ + 1) & 15;                                             \
        _Pragma("unroll")                                                     \
        for (int fm = 0; fm < 4; ++fm)                                        \
            KNEXT[fm] = *(const short8*)&kb[((((size_t)tn_ * 4 + fm) * 64) + lane) * 8]; \
    }                                                                         \
    float mx0 = fmaxf(fmaxf(s0_[0][0], s0_[0][1]), fmaxf(s0_[0][2], s0_[0][3])); \
    float mx1 = fmaxf(fmaxf(s1_[0][0], s1_[0][1]), fmaxf(s1_[0][2], s1_[0][3])); \
    _Pragma("unroll")                                                         \
    for (int fm = 1; fm < 4; ++fm) {                                          \
        mx0 = fmaxf(mx0, fmaxf(fmaxf(s0_[fm][0], s0_[fm][1]), fmaxf(s0_[fm][2], s0_[fm][3]))); \
        mx1 = fmaxf(mx1, fmaxf(fmaxf(s1_[fm][0], s1_[fm][1]), fmaxf(s1_[fm][2], s1_[fm][3]))); \
    }                                                                         \
    mx0 = fmaxf(mx0, __shfl_xor(mx0, 16)); mx0 = fmaxf(mx0, __shfl_xor(mx0, 32)); \
    mx1 = fmaxf(mx1, __shfl_xor(mx1, 16)); mx1 = fmaxf(mx1, __shfl_xor(mx1, 32)); \
    bool need_ = (mx0 > m_run0 + 11.0f) || (mx1 > m_run1 + 11.0f);            \
    if (__any(need_)) {                                                       \
        float mn0 = fmaxf(m_run0, mx0), f0 = exp2f(m_run0 - mn0);             \
        float mn1 = fmaxf(m_run1, mx1), f1 = exp2f(m_run1 - mn1);             \
        m_run0 = mn0; m_run1 = mn1; l_run0 *= f0; l_run1 *= f1;               \
        _Pragma("unroll")                                                     \
        for (int rr = 0; rr < 4; ++rr) {                                      \
            float fb0 = __shfl(f0, lhi * 4 + rr);                             \
            float fb1 = __shfl(f1, lhi * 4 + rr);                             \
            _Pragma("unroll")                                                 \
            for (int fdv = 0; fdv < 8; ++fdv) {                               \
                acc[0][fdv][rr] *= fb0;                                       \
                acc[1][fdv][rr] *= fb1;                                       \
            }                                                                 \
        }                                                                     \
    }                                                                         \
    float rs0 = 0.f, rs1 = 0.f;                                               \
    _Pragma("unroll")                                                         \
    for (int fm = 0; fm < 4; ++fm) {                                          \
        float p0 = exp2f(s0_[fm][0] - m_run0), p1 = exp2f(s0_[fm][1] - m_run0); \
        float p2 = exp2f(s0_[fm][2] - m_run0), p3 = exp2f(s0_[fm][3] - m_run0); \
        rs0 += (p0 + p1) + (p2 + p3);                                         \
        *(ull*)&pw[l16 * 72 + fm * 16 + lhi * 4] = pack4bf(p0, p1, p2, p3);   \
        float t0 = exp2f(s1_[fm][0] - m_run1), t1 = exp2f(s1_[fm][1] - m_run1); \
        float t2 = exp2f(s1_[fm][2] - m_run1), t3 = exp2f(s1_[fm][3] - m_run1); \
        rs1 += (t0 + t1) + (t2 + t3);                                         \
        *(ull*)&pw[(16 + l16) * 72 + fm * 16 + lhi * 4] = pack4bf(t0, t1, t2, t3); \
    }                                                                         \
    rs0 += __shfl_xor(rs0, 16); rs0 += __shfl_xor(rs0, 32);                   \
    rs1 += __shfl_xor(rs1, 16); rs1 += __shfl_xor(rs1, 32);                   \
    l_run0 += rs0; l_run1 += rs1;                                             \
    asm volatile("s_waitcnt lgkmcnt(0)" ::: "memory");                        \
    _Pragma("unroll")                                                         \
    for (int kc = 0; kc < 2; ++kc) {                                          \
        short8 pf0 = *(const short8*)&pw[l16 * 72 + kc * 32 + lhi * 8];       \
        short8 pf1 = *(const short8*)&pw[(16 + l16) * 72 + kc * 32 + lhi * 8]; \
        _Pragma("unroll")                                                     \
        for (int fdv = 0; fdv < 8; ++fdv) {                                   \
            acc[0][fdv] = __builtin_amdgcn_mfma_f32_16x16x32_bf16(pf0, vf_[kc * 8 + fdv], acc[0][fdv], 0, 0, 0); \
            acc[1][fdv] = __builtin_amdgcn_mfma_f32_16x16x32_bf16(pf1, vf_[kc * 8 + fdv], acc[1][fdv], 0, 0, 0); \
        }                                                                     \
    }                                                                         \
}

__global__ __launch_bounds__(64) void attn_kernel(
    const short* __restrict__ qlin, const short* __restrict__ klin,
    const short* __restrict__ vlin, const float* __restrict__ st,
    short* __restrict__ outp)
{
    __shared__ short pw[32 * 72];
    const int id0 = blockIdx.x;                       // 2048
    const int swz = (id0 & 7) * 256 + (id0 >> 3);     // XCD-contiguous chunks
    const int qt = swz & 31, bh = swz >> 5;
    const int h = bh & 7, b = bh >> 3;
    const int q0 = qt * 32;
    const int lane = threadIdx.x;
    const int l16 = lane & 15, lhi = lane >> 4;

    const short* qb = qlin + (size_t)bh * 32768;
    const short* kb = klin + (size_t)bh * 32768;
    const short* vb = vlin + (size_t)bh * 131072;

    short8 qf0 = *(const short8*)&qb[(((size_t)qt * 2 + 0) * 64 + lane) * 8];
    short8 qf1 = *(const short8*)&qb[(((size_t)qt * 2 + 1) * 64 + lane) * 8];

    f32x4 acc[2][8];
    #pragma unroll
    for (int i = 0; i < 2; ++i)
        #pragma unroll
        for (int j = 0; j < 8; ++j) acc[i][j] = (f32x4){0.f, 0.f, 0.f, 0.f};
    float m_run0 = -1e30f, m_run1 = -1e30f, l_run0 = 0.f, l_run1 = 0.f;

    short8 kfA[4], kfB[4];
    #pragma unroll
    for (int fm = 0; fm < 4; ++fm)
        kfA[fm] = *(const short8*)&kb[((size_t)fm * 64 + lane) * 8];

    for (int mt = 0; mt < 16; mt += 2) {
        ATTN_TILE(mt,     kfA, kfB)
        ATTN_TILE(mt + 1, kfB, kfA)
    }

    // epilogue: V BN (commuted), normalize, gelu, store
    float scv[8], shv[8];
    #pragma unroll
    for (int fdv = 0; fdv < 8; ++fdv) {
        int cv = h * 192 + 64 + fdv * 16 + l16;
        scv[fdv] = st[cv * 2]; shv[fdv] = st[cv * 2 + 1];
    }
    #pragma unroll
    for (int rr = 0; rr < 4; ++rr) {
        float inv0 = 1.0f / __shfl(l_run0, lhi * 4 + rr);
        float inv1 = 1.0f / __shfl(l_run1, lhi * 4 + rr);
        size_t row0 = (size_t)b * NPIX + q0 + lhi * 4 + rr;
        #pragma unroll
        for (int fdv = 0; fdv < 8; ++fdv) {
            float o0 = acc[0][fdv][rr] * inv0 * scv[fdv] + shv[fdv];
            float o1 = acc[1][fdv][rr] * inv1 * scv[fdv] + shv[fdv];
            outp[row0 * 1024 + h * 128 + fdv * 16 + l16] = f2bf(gelu_exact(o0));
            outp[(row0 + 16) * 1024 + h * 128 + fdv * 16 + l16] = f2bf(gelu_exact(o1));
        }
    }
}

// ---------------------------------------------------------------------------
// x2 = x_tf + bn(merge_bf); writes fp32 + bf16. 8 ch/thread.
// ---------------------------------------------------------------------------
__global__ __launch_bounds__(256) void x2_kernel(
    const short* __restrict__ raw, const float* __restrict__ st,
    const float* __restrict__ xtf, float* __restrict__ x2f, short* __restrict__ x2bf)
{
    int t = blockIdx.x * 256 + threadIdx.x;     // ROWS*48
    int row = t / 48, c = (t % 48) * 8;
    size_t idx = (size_t)row * 384 + c;
    short8 v8 = *(const short8*)&raw[idx];
    float o[8];
    #pragma unroll
    for (int j = 0; j < 8; ++j) {
        float sc = st[(c + j) * 2], sh = st[(c + j) * 2 + 1];
        o[j] = xtf[idx + j] + bf2f(v8[j]) * sc + sh;
    }
    *(float4*)&x2f[idx]     = make_float4(o[0], o[1], o[2], o[3]);
    *(float4*)&x2f[idx + 4] = make_float4(o[4], o[5], o[6], o[7]);
    *(ull*)&x2bf[idx]     = pack4bf(o[0], o[1], o[2], o[3]);
    *(ull*)&x2bf[idx + 4] = pack4bf(o[4], o[5], o[6], o[7]);
}

// ---------------------------------------------------------------------------
// h = gelu(bn(fc1_bf)) -> bf16. 8 ch/thread.
// ---------------------------------------------------------------------------
__global__ __launch_bounds__(256) void h_kernel(
    const short* __restrict__ raw, const float* __restrict__ st, short* __restrict__ hbf)
{
    int t = blockIdx.x * 256 + threadIdx.x;     // ROWS*96
    int row = t / 96, c = (t % 96) * 8;
    size_t idx = (size_t)row * 768 + c;
    short8 v8 = *(const short8*)&raw[idx];
    float o[8];
    #pragma unroll
    for (int j = 0; j < 8; ++j) {
        float sc = st[(c + j) * 2], sh = st[(c + j) * 2 + 1];
        o[j] = gelu_exact(bf2f(v8[j]) * sc + sh);
    }
    *(ull*)&hbf[idx]     = pack4bf(o[0], o[1], o[2], o[3]);
    *(ull*)&hbf[idx + 4] = pack4bf(o[4], o[5], o[6], o[7]);
}

// ---------------------------------------------------------------------------
// out[b][c][n] = x2f[row][c] + bn(fc2_raw[row][c])  (transposed store)
// ---------------------------------------------------------------------------
__global__ __launch_bounds__(256) void final_tr(
    const float* __restrict__ raw, const float* __restrict__ st,
    const float* __restrict__ x2f, float* __restrict__ out)
{
    __shared__ float ls[64][65];
    const int b = blockIdx.z, c0 = blockIdx.y * 64, n0 = blockIdx.x * 64;
    const int rl = threadIdx.x >> 6, ll = threadIdx.x & 63;
    const int c = c0 + ll;
    const float sc = st[c * 2], sh = st[c * 2 + 1];
    #pragma unroll
    for (int it = 0; it < 16; ++it) {
        int n = rl + it * 4;
        size_t idx = ((size_t)b * NPIX + n0 + n) * 384 + c;
        ls[n][ll] = x2f[idx] + raw[idx] * sc + sh;
    }
    __syncthreads();
    #pragma unroll
    for (int it = 0; it < 16; ++it) {
        int cr = rl + it * 4;
        out[((size_t)b * 384 + c0 + cr) * NPIX + n0 + ll] = ls[ll][cr];
    }
}

// ---------------------------------------------------------------------------
extern "C" void kernel_launch(void* const* d_in, const int* in_sizes, int n_in,
                              void* d_out, int out_size, void* d_ws, size_t ws_size,
                              hipStream_t stream)
{
    const float* x       = (const float*)d_in[0];
    const float* w_qkv   = (const float*)d_in[1];
    const float* g_qkv   = (const float*)d_in[2];
    const float* b_qkv   = (const float*)d_in[3];
    const float* w_merge = (const float*)d_in[4];
    const float* g_merge = (const float*)d_in[5];
    const float* b_merge = (const float*)d_in[6];
    const float* w_fc1   = (const float*)d_in[7];
    const float* g_fc1   = (const float*)d_in[8];
    const float* b_fc1   = (const float*)d_in[9];
    const float* w_fc2   = (const float*)d_in[10];
    const float* g_fc2   = (const float*)d_in[11];
    const float* b_fc2   = (const float*)d_in[12];
    float* out = (float*)d_out;

    char* ws = (char*)d_ws;
    short* wq_bf   = (short*)(ws + 0);
    short* wm_bf   = (short*)(ws + 1179648);
    short* wf1_bf  = (short*)(ws + 1966080);
    short* wf2_bf  = (short*)(ws + 2555904);
    short* x_bf    = (short*)(ws + 3145728);      // 6,291,456
    float* x_tf    = (float*)(ws + 9437184);      // 12,582,912
    short* qkv_bf  = (short*)(ws + 22020096);     // 25,165,824 (dead after repack)
    short* attn_bf = (short*)(ws + 22020096);     // 16,777,216 (reuse, after repack)
    float* fc2_raw = (float*)(ws + 22020096);     // 12,582,912 (reuse, after merge gemm)
    short* q_lin   = (short*)(ws + 47185920);     // 4,194,304
    short* merge_bf= (short*)(ws + 47185920);     // 6,291,456 (reuse q/k_lin after attn)
    short* k_lin   = (short*)(ws + 51380224);     // 4,194,304
    short* v_lin   = (short*)(ws + 55574528);     // 16,777,216
    float* x2_f    = (float*)(ws + 55574528);     // 12,582,912 (reuse v_lin after attn)
    short* x2_bf   = (short*)(ws + 72351744);     // 6,291,456
    short* fc1_bf  = (short*)(ws + 78643200);     // 12,582,912
    short* h_bf    = (short*)(ws + 91226112);     // 12,582,912
    float* sums    = (float*)(ws + 103809024);    // 24,576
    float* stats   = (float*)(ws + 103833600);    // 24,576

    float* sums_qkv = sums;
    float* sums_mg  = sums + 1536 * 2;
    float* sums_f1  = sums + (1536 + 384) * 2;
    float* sums_f2  = sums + (1536 + 384 + 768) * 2;
    float* st_qkv = stats;
    float* st_mg  = stats + 1536 * 2;
    float* st_f1  = stats + (1536 + 384) * 2;
    float* st_f2  = stats + (1536 + 384 + 768) * 2;

    prep_kernel<<<1537, 256, 0, stream>>>(x, w_qkv, w_merge, w_fc1, w_fc2,
                                          wq_bf, wm_bf, wf1_bf, wf2_bf,
                                          x_bf, x_tf, sums);

    gemm_bf16<short><<<dim3(64, 12), 256, 0, stream>>>(
        x_bf, wq_bf, qkv_bf, sums_qkv, 1536, 384);
    bn_finalize<<<6, 256, 0, stream>>>(sums_qkv, g_qkv, b_qkv, st_qkv, 1536);

    repack_qkv<<<dim3(16, 64), 256, 0, stream>>>(qkv_bf, st_qkv, q_lin, k_lin, v_lin);

    attn_kernel<<<2048, 64, 0, stream>>>(q_lin, k_lin, v_lin, st_qkv, attn_bf);

    gemm_bf16<short><<<dim3(64, 3), 256, 0, stream>>>(
        attn_bf, wm_bf, merge_bf, sums_mg, 384, 1024);
    bn_finalize<<<2, 256, 0, stream>>>(sums_mg, g_merge, b_merge, st_mg, 384);

    x2_kernel<<<1536, 256, 0, stream>>>(merge_bf, st_mg, x_tf, x2_f, x2_bf);

    gemm_bf16<short><<<dim3(64, 6), 256, 0, stream>>>(
        x2_bf, wf1_bf, fc1_bf, sums_f1, 768, 384);
    bn_finalize<<<3, 256, 0, stream>>>(sums_f1, g_fc1, b_fc1, st_f1, 768);

    h_kernel<<<3072, 256, 0, stream>>>(fc1_bf, st_f1, h_bf);

    gemm_bf16<float><<<dim3(64, 3), 256, 0, stream>>>(
        h_bf, wf2_bf, fc2_raw, sums_f2, 384, 768);
    bn_finalize<<<2, 256, 0, stream>>>(sums_f2, g_fc2, b_fc2, st_f2, 384);

    final_tr<<<dim3(16, 6, 8), 256, 0, stream>>>(fc2_raw, st_f2, x2_f, out);
}